// Round 5
// baseline (177.516 us; speedup 1.0000x reference)
//
#include <hip/hip_runtime.h>

// GraphSAGE 2-layer: N=50000, D=128, DEG=16.
// R7: mean-first split + chunk-local gather. Features stored chunk-major
//     [4][N][32] bf16 (3.2 MB/chunk fits per-XCD L2). gather_mean runs 4
//     chunk passes (grid.y) so the concurrent block window gathers from an
//     L2-resident table (~200cy vs ~450cy -> ~2x gather rate, latency-bound
//     per R5/R6 evidence). GEMM = relu([x|M]@W+b), A staged via swizzled
//     global_load_lds from chunk-major buffers. 5 launches.
typedef __attribute__((ext_vector_type(8))) short short8;
typedef __attribute__((ext_vector_type(4))) float f32x4;
typedef __attribute__((ext_vector_type(2))) float f32x2;

#define N_NODES 50000
#define D 128
#define DEG 16
#define K2 256
#define CHSZ (N_NODES * 64u)   // bytes per 32-dim chunk region = 3,200,000

static __device__ __forceinline__ unsigned short f2b(float f) {
    union { float f; unsigned int u; } v; v.f = f;
    return (unsigned short)((v.u + 0x7fffu + ((v.u >> 16) & 1u)) >> 16);
}

// ---- prep ----
// blocks 0..31: pack W1,W2 ((2D,D) row-major) into fragment order (R5 layout):
//   o = w*8192 + kk*1024 + ct*512 + lane*8 + e  (shorts)
//   k = kk*32 + (lane>>4)*8 + e, n = w*32 + 2*(lane&15) + ct
// blocks 32..: x (N,128) f32 -> xcm[4][N][32] bf16 chunk-major.
__global__ void prep(const float* __restrict__ x, unsigned short* __restrict__ xcm,
                     const float* __restrict__ W1, const float* __restrict__ W2,
                     unsigned short* __restrict__ Wf1, unsigned short* __restrict__ Wf2) {
    int b = blockIdx.x;
    if (b < 32) {
        int o  = (b * 256 + threadIdx.x) * 4;   // short index, 0..32764
        int e0 = o & 7;
        int l  = (o >> 3) & 63;
        int ct = (o >> 9) & 1;
        int kk = (o >> 10) & 7;
        int w  = o >> 13;
        int n  = w * 32 + ((l & 15) << 1) + ct;
        int kb = kk * 32 + (l >> 4) * 8 + e0;
        ushort4 a, c;
        a.x = f2b(W1[(kb + 0) * D + n]);
        a.y = f2b(W1[(kb + 1) * D + n]);
        a.z = f2b(W1[(kb + 2) * D + n]);
        a.w = f2b(W1[(kb + 3) * D + n]);
        *(ushort4*)(Wf1 + o) = a;
        c.x = f2b(W2[(kb + 0) * D + n]);
        c.y = f2b(W2[(kb + 1) * D + n]);
        c.z = f2b(W2[(kb + 2) * D + n]);
        c.w = f2b(W2[(kb + 3) * D + n]);
        *(ushort4*)(Wf2 + o) = c;
    } else {
        // 3125 blocks x 256 thr x 16B = 12.8 MB exactly
        unsigned o = ((unsigned)(b - 32) * 256u + threadIdx.x) * 16u;  // byte off in xcm
        unsigned rowidx = o >> 6;                 // 0..199999
        unsigned c = rowidx / N_NODES;            // chunk 0..3
        unsigned n = rowidx - c * N_NODES;
        unsigned d0 = (o & 63u) >> 1;             // 0,8,16,24
        const float* src = x + n * 128 + c * 32 + d0;
        float4 v0 = *(const float4*)src;
        float4 v1 = *(const float4*)(src + 4);
        union { unsigned short u[8]; short8 s8; } m;
        m.u[0] = f2b(v0.x); m.u[1] = f2b(v0.y); m.u[2] = f2b(v0.z); m.u[3] = f2b(v0.w);
        m.u[4] = f2b(v1.x); m.u[5] = f2b(v1.y); m.u[6] = f2b(v1.z); m.u[7] = f2b(v1.w);
        *(short8*)((char*)xcm + o) = m.s8;
    }
}

// ---- gather_mean: Mcm[c][n][:] = (1/16) * sum_j fcm[c][nbr[n][j]][:] ----
// grid = (782, 4); blockIdx.y = chunk (3.2 MB, per-XCD-L2-resident window).
// block = 256 thr = 64 rows x 4 slices of 16B.
__global__ __launch_bounds__(256, 4)
void gather_mean(const unsigned short* __restrict__ fcm,
                 const int* __restrict__ nbr,
                 unsigned short* __restrict__ Mcm)
{
    __shared__ __align__(16) int Nl[1024];
    const int tid  = threadIdx.x;
    const int row0 = blockIdx.x * 64;
    const char* base = (const char*)fcm + blockIdx.y * CHSZ;

    int g = row0 * DEG + tid * 4;
    int gmax = N_NODES * DEG - 4;
    if (g > gmax) g = gmax;
    *(int4*)(Nl + tid * 4) = *(const int4*)(nbr + g);
    __syncthreads();

    const int r = tid >> 2, s = tid & 3;
    const int grow = row0 + r;
    const unsigned sB = (unsigned)s * 16u;

    int4 i0 = *(const int4*)(Nl + r * 16);
    int4 i1 = *(const int4*)(Nl + r * 16 + 4);
    int4 i2 = *(const int4*)(Nl + r * 16 + 8);
    int4 i3 = *(const int4*)(Nl + r * 16 + 12);
    int ids[16] = { i0.x, i0.y, i0.z, i0.w, i1.x, i1.y, i1.z, i1.w,
                    i2.x, i2.y, i2.z, i2.w, i3.x, i3.y, i3.z, i3.w };

    short8 v[16];
    #pragma unroll
    for (int j = 0; j < 16; ++j)
        v[j] = *(const short8*)(base + (((unsigned)ids[j]) << 6) + sB);

    f32x2 am[4];
    #pragma unroll
    for (int i = 0; i < 4; ++i) am[i] = (f32x2){0.f, 0.f};
    #pragma unroll
    for (int j = 0; j < 16; ++j) {
        union { short8 s8; unsigned u[4]; } vv; vv.s8 = v[j];
        #pragma unroll
        for (int i = 0; i < 4; ++i) {
            unsigned ui = vv.u[i];
            f32x2 e;
            e.x = __uint_as_float(ui << 16);
            e.y = __uint_as_float(ui & 0xffff0000u);
            am[i] += e;
        }
    }

    if (grow < N_NODES) {
        union { unsigned short u[8]; short8 s8; } m;
        #pragma unroll
        for (int i = 0; i < 4; ++i) {
            m.u[2 * i]     = f2b(am[i].x * 0.0625f);
            m.u[2 * i + 1] = f2b(am[i].y * 0.0625f);
        }
        *(short8*)((char*)Mcm + blockIdx.y * CHSZ + (unsigned)grow * 64u + sB) = m.s8;
    }
}

// ---- gemm: out = relu( [feat | M] @ W + b ) ----
// BM=32, 256 thr, A tile (32 x 512B) staged via swizzled global_load_lds from
// chunk-major feat/M. OUT_F32: f32 row-major (layer 2); else bf16 chunk-major.
template <int OUT_F32>
__global__ __launch_bounds__(256, 4)
void gemm(const unsigned short* __restrict__ fcm,
          const unsigned short* __restrict__ Mcm,
          const unsigned short* __restrict__ wf,
          const float* __restrict__ bias,
          void* __restrict__ out)
{
    __shared__ __align__(16) char Al[32 * 512];   // 16 KB, XOR-swizzled rows
    const int tid  = threadIdx.x;
    const int row0 = blockIdx.x * 32;
    const int wave = tid >> 6;
    const int lane = tid & 63;
    const int quad = lane >> 4;
    const int l16  = lane & 15;

    // stage A: 4 rounds x (256 lanes x 16B). LDS dest linear;
    // LDS[row][cb] = concat(feat,M)[row][cb ^ ((row&7)<<4)] via per-lane src.
    #pragma unroll
    for (int i = 0; i < 4; ++i) {
        unsigned o    = (unsigned)i * 4096u + (unsigned)tid * 16u;
        unsigned row  = o >> 9;
        unsigned colb = o & 511u;
        unsigned scol = colb ^ ((row & 7u) << 4);   // bits 4-6: stays in half
        int grow = row0 + (int)row;
        if (grow >= N_NODES) grow = N_NODES - 1;
        const unsigned short* buf = (scol < 256u) ? fcm : Mcm;
        unsigned cb = scol & 255u;
        const char* src = (const char*)buf + (cb >> 6) * CHSZ
                          + (unsigned)grow * 64u + (cb & 63u);
        __builtin_amdgcn_global_load_lds(
            (const __attribute__((address_space(1))) unsigned int*)src,
            (__attribute__((address_space(3))) unsigned int*)
                (Al + i * 4096 + wave * 1024),
            16, 0, 0);
    }

    // B fragments (fragment-packed, fully coalesced)
    const unsigned short* wfw = wf + wave * 8192;
    short8 bfrag[8][2];
    #pragma unroll
    for (int kk = 0; kk < 8; ++kk)
        #pragma unroll
        for (int ct = 0; ct < 2; ++ct)
            bfrag[kk][ct] = *(const short8*)(wfw + kk * 1024 + ct * 512 + lane * 8);

    __syncthreads();   // drains global_load_lds before ds_read

    f32x4 acc[2][2];
    #pragma unroll
    for (int rt = 0; rt < 2; ++rt)
        #pragma unroll
        for (int ct = 0; ct < 2; ++ct)
            acc[rt][ct] = (f32x4){0.f, 0.f, 0.f, 0.f};

    #pragma unroll
    for (int kk = 0; kk < 8; ++kk) {
        short8 af[2];
        #pragma unroll
        for (int rt = 0; rt < 2; ++rt) {
            unsigned row  = (unsigned)(rt * 16 + l16);
            unsigned byte = row * 512u + (unsigned)kk * 64u + (unsigned)quad * 16u;
            byte ^= (row & 7u) << 4;
            af[rt] = *(const short8*)(Al + byte);
        }
        #pragma unroll
        for (int rt = 0; rt < 2; ++rt)
            #pragma unroll
            for (int ct = 0; ct < 2; ++ct)
                acc[rt][ct] = __builtin_amdgcn_mfma_f32_16x16x32_bf16(
                    af[rt], bfrag[kk][ct], acc[rt][ct], 0, 0, 0);
    }

    // epilogue: adjacent col pair per thread
    const int col0 = wave * 32 + (l16 << 1);
    float2 bv = *(const float2*)(bias + col0);
    #pragma unroll
    for (int rt = 0; rt < 2; ++rt) {
        int gb = row0 + rt * 16 + quad * 4;
        #pragma unroll
        for (int r = 0; r < 4; ++r) {
            int grow = gb + r;
            if (grow >= N_NODES) continue;
            float v0 = acc[rt][0][r] + bv.x;
            float v1 = acc[rt][1][r] + bv.y;
            v0 = v0 > 0.f ? v0 : 0.f;
            v1 = v1 > 0.f ? v1 : 0.f;
            if (OUT_F32) {
                f32x2 o2; o2.x = v0; o2.y = v1;
                *(f32x2*)((float*)out + grow * D + col0) = o2;
            } else {
                unsigned u = (unsigned)f2b(v0) | ((unsigned)f2b(v1) << 16);
                *(unsigned*)((char*)out + (col0 >> 5) * CHSZ
                             + (unsigned)grow * 64u + (col0 & 31) * 2) = u;
            }
        }
    }
}

extern "C" void kernel_launch(void* const* d_in, const int* in_sizes, int n_in,
                              void* d_out, int out_size, void* d_ws, size_t ws_size,
                              hipStream_t stream) {
    const float* x  = (const float*)d_in[0];
    const int*   nb = (const int*)d_in[1];
    const float* W1 = (const float*)d_in[2];
    const float* b1 = (const float*)d_in[3];
    const float* W2 = (const float*)d_in[4];
    const float* b2 = (const float*)d_in[5];

    char* ws = (char*)d_ws;
    unsigned short* Wf1  = (unsigned short*)(ws);                       // 64 KB
    unsigned short* Wf2  = (unsigned short*)(ws + 65536);               // 64 KB
    unsigned short* xcm  = (unsigned short*)(ws + 131072);              // 12.8 MB
    unsigned short* Mcm  = (unsigned short*)(ws + 131072 + 12800000);   // 12.8 MB
    unsigned short* h1cm = (unsigned short*)(ws + 131072 + 25600000);   // 12.8 MB

    prep<<<32 + 3125, 256, 0, stream>>>(x, xcm, W1, W2, Wf1, Wf2);

    const int ggrid = (N_NODES + 63) / 64;   // 782 (x), chunks in y
    const int mgrid = (N_NODES + 31) / 32;   // 1563

    gather_mean<<<dim3(ggrid, 4), 256, 0, stream>>>(xcm, nb, Mcm);
    gemm<0><<<mgrid, 256, 0, stream>>>(xcm, Mcm, Wf1, b1, h1cm);
    gather_mean<<<dim3(ggrid, 4), 256, 0, stream>>>(h1cm, nb, Mcm);
    gemm<1><<<mgrid, 256, 0, stream>>>(h1cm, Mcm, Wf2, b2, d_out);
}

// Round 7
// 124.856 us; speedup vs baseline: 1.4218x; 1.4218x over previous
//
#include <hip/hip_runtime.h>

// GraphSAGE 2-layer: N=50000, D=128, DEG=16.
// R9: R4 monolithic structure (BM=32, 4 blocks/CU) + fp8-e4m3 neighbor table:
//     gather reads 128B rows (1 line) instead of 256B (2 lines) -> halves
//     gather bytes AND line-touches (latency/concurrency-bound per R5-R7).
//     Self term + GEMM stay bf16. HW cvt_pk fp8<->f32. Col-interleaved
//     fragments -> paired epilogue stores. 3 launches.
typedef __attribute__((ext_vector_type(8))) short short8;
typedef __attribute__((ext_vector_type(4))) float f32x4;
typedef __attribute__((ext_vector_type(2))) float f32x2;

#define N_NODES 50000
#define D 128
#define DEG 16
#define BM 32

static __device__ __forceinline__ unsigned short f2b(float f) {
    union { float f; unsigned int u; } v; v.f = f;
    return (unsigned short)((v.u + 0x7fffu + ((v.u >> 16) & 1u)) >> 16);
}

// ---- prep ----
// blocks 0..31: pack W1,W2 ((2D,D) row-major) into fragment order:
//   o = w*8192 + kk*1024 + ct*512 + lane*8 + e  (shorts)
//   k = kk*32 + (lane>>4)*8 + e,  n = w*32 + 2*(lane&15) + ct  (col-interleaved)
// blocks 32..: x -> bf16 (xb) and fp8-e4m3 (xq).
__global__ void prep(const float* __restrict__ x, unsigned short* __restrict__ xb,
                     unsigned char* __restrict__ xq,
                     const float* __restrict__ W1, const float* __restrict__ W2,
                     unsigned short* __restrict__ Wf1, unsigned short* __restrict__ Wf2) {
    int b = blockIdx.x;
    if (b < 32) {
        int o  = (b * 256 + threadIdx.x) * 4;
        int e0 = o & 7;
        int l  = (o >> 3) & 63;
        int ct = (o >> 9) & 1;
        int kk = (o >> 10) & 7;
        int w  = o >> 13;
        int n  = w * 32 + ((l & 15) << 1) + ct;
        int kb = kk * 32 + (l >> 4) * 8 + e0;
        ushort4 a, c;
        a.x = f2b(W1[(kb + 0) * D + n]);
        a.y = f2b(W1[(kb + 1) * D + n]);
        a.z = f2b(W1[(kb + 2) * D + n]);
        a.w = f2b(W1[(kb + 3) * D + n]);
        *(ushort4*)(Wf1 + o) = a;
        c.x = f2b(W2[(kb + 0) * D + n]);
        c.y = f2b(W2[(kb + 1) * D + n]);
        c.z = f2b(W2[(kb + 2) * D + n]);
        c.w = f2b(W2[(kb + 3) * D + n]);
        *(ushort4*)(Wf2 + o) = c;
    } else {
        int i = ((b - 32) * 256 + threadIdx.x) * 4;
        if (i < N_NODES * D) {
            float4 v = *(const float4*)(x + i);
            ushort4 o4;
            o4.x = f2b(v.x); o4.y = f2b(v.y); o4.z = f2b(v.z); o4.w = f2b(v.w);
            *(ushort4*)(xb + i) = o4;
            int q = __builtin_amdgcn_cvt_pk_fp8_f32(v.x, v.y, 0, false);
            q = __builtin_amdgcn_cvt_pk_fp8_f32(v.z, v.w, q, true);
            *(unsigned*)(xq + i) = (unsigned)q;
        }
    }
}

// ---- fused layer: out = relu( [feat | mean_nbr(feat_q)] @ W + b ) ----
// OUT_BF16=1: write bf16 (h1) + fp8 (h1q). OUT_BF16=0: write f32 final.
template <int OUT_BF16>
__global__ __launch_bounds__(256, 4)
void sage_layer(const unsigned short* __restrict__ feat,   // N x D bf16
                const unsigned char* __restrict__ featq,   // N x D fp8
                const int* __restrict__ nbr,               // N x DEG
                const unsigned short* __restrict__ wf,     // fragment-packed bf16
                const float* __restrict__ bias,            // D f32
                void* __restrict__ out,
                unsigned char* __restrict__ outq)          // N x D fp8 (OUT_BF16)
{
    __shared__ __align__(16) unsigned short Hl[BM * 264];  // A tile, row stride 264
    __shared__ int Nl[BM * DEG];                           // 512 neighbor ids
    const int tid  = threadIdx.x;
    const int row0 = blockIdx.x * BM;

    if (tid < 128) {
        int g = row0 * DEG + tid * 4;
        int gmax = N_NODES * DEG - 4;
        if (g > gmax) g = gmax;              // tail clamp; extra rows unused
        *(int4*)(Nl + tid * 4) = *(const int4*)(nbr + g);
    }
    __syncthreads();

    const char* fb = (const char*)feat;      // bf16 rows: 256B
    const char* qb = (const char*)featq;     // fp8 rows: 128B

    // ---- gather: 2 (row, 8-dim-slice) pairs per thread; 16 8B-loads in flight
    #pragma unroll
    for (int p = 0; p < 2; ++p) {
        int a = tid + p * 256;
        int r = a >> 4;                      // 0..31
        int s = a & 15;                      // 8-dim slice
        int grow = row0 + r;
        if (grow >= N_NODES) grow = N_NODES - 1;
        short8 self = *(const short8*)(fb + (unsigned)grow * 256u + (unsigned)s * 16u);

        int4 i0 = *(const int4*)(Nl + r * 16);
        int4 i1 = *(const int4*)(Nl + r * 16 + 4);
        int4 i2 = *(const int4*)(Nl + r * 16 + 8);
        int4 i3 = *(const int4*)(Nl + r * 16 + 12);
        int ids[16] = { i0.x, i0.y, i0.z, i0.w, i1.x, i1.y, i1.z, i1.w,
                        i2.x, i2.y, i2.z, i2.w, i3.x, i3.y, i3.z, i3.w };

        uint2 v[16];
        #pragma unroll
        for (int j = 0; j < 16; ++j)
            v[j] = *(const uint2*)(qb + (((unsigned)ids[j]) << 7) + (unsigned)s * 8u);

        f32x2 am[4];
        #pragma unroll
        for (int i = 0; i < 4; ++i) am[i] = (f32x2){0.f, 0.f};
        #pragma unroll
        for (int j = 0; j < 16; ++j) {
            am[0] += __builtin_amdgcn_cvt_pk_f32_fp8(v[j].x, false);
            am[1] += __builtin_amdgcn_cvt_pk_f32_fp8(v[j].x, true);
            am[2] += __builtin_amdgcn_cvt_pk_f32_fp8(v[j].y, false);
            am[3] += __builtin_amdgcn_cvt_pk_f32_fp8(v[j].y, true);
        }

        unsigned short* hr = Hl + r * 264 + s * 8;
        *(short8*)(hr) = self;
        union { unsigned short u[8]; short8 s8; } m;
        #pragma unroll
        for (int i = 0; i < 4; ++i) {
            m.u[2 * i]     = f2b(am[i].x * 0.0625f);
            m.u[2 * i + 1] = f2b(am[i].y * 0.0625f);
        }
        *(short8*)(hr + D) = m.s8;
    }

    // ---- B fragments (fragment-packed: 64 lanes x 16B contiguous per load)
    const int lane = tid & 63;
    const int w    = tid >> 6;
    const int quad = lane >> 4;
    const int l16  = lane & 15;
    const unsigned short* wfw = wf + w * 8192;
    short8 bfrag[8][2];
    #pragma unroll
    for (int kk = 0; kk < 8; ++kk)
        #pragma unroll
        for (int ct = 0; ct < 2; ++ct)
            bfrag[kk][ct] = *(const short8*)(wfw + kk * 1024 + ct * 512 + lane * 8);

    __syncthreads();

    // ---- MFMA: 32 rows (2 rt) x 32 cols (2 ct, col-interleaved) per wave
    f32x4 acc[2][2];
    #pragma unroll
    for (int rt = 0; rt < 2; ++rt)
        #pragma unroll
        for (int ct = 0; ct < 2; ++ct)
            acc[rt][ct] = (f32x4){0.f, 0.f, 0.f, 0.f};

    #pragma unroll
    for (int kk = 0; kk < 8; ++kk) {
        short8 af[2];
        #pragma unroll
        for (int rt = 0; rt < 2; ++rt)
            af[rt] = *(const short8*)(&Hl[(rt * 16 + l16) * 264 + kk * 32 + quad * 8]);
        #pragma unroll
        for (int rt = 0; rt < 2; ++rt)
            #pragma unroll
            for (int ct = 0; ct < 2; ++ct)
                acc[rt][ct] = __builtin_amdgcn_mfma_f32_16x16x32_bf16(
                    af[rt], bfrag[kk][ct], acc[rt][ct], 0, 0, 0);
    }

    // ---- epilogue: adjacent col pair (col0, col0+1) per thread
    const int col0 = w * 32 + (l16 << 1);
    float2 bv = *(const float2*)(bias + col0);
    #pragma unroll
    for (int rt = 0; rt < 2; ++rt) {
        int gb = row0 + rt * 16 + quad * 4;
        #pragma unroll
        for (int r = 0; r < 4; ++r) {
            int grow = gb + r;
            if (grow >= N_NODES) continue;
            float v0 = acc[rt][0][r] + bv.x;
            float v1 = acc[rt][1][r] + bv.y;
            v0 = v0 > 0.f ? v0 : 0.f;
            v1 = v1 > 0.f ? v1 : 0.f;
            if (OUT_BF16) {
                unsigned u = (unsigned)f2b(v0) | ((unsigned)f2b(v1) << 16);
                *(unsigned*)((unsigned short*)out + grow * D + col0) = u;
                int q = __builtin_amdgcn_cvt_pk_fp8_f32(v0, v1, 0, false);
                *(unsigned short*)(outq + grow * D + col0) = (unsigned short)q;
            } else {
                f32x2 o2; o2.x = v0; o2.y = v1;
                *(f32x2*)((float*)out + grow * D + col0) = o2;
            }
        }
    }
}

extern "C" void kernel_launch(void* const* d_in, const int* in_sizes, int n_in,
                              void* d_out, int out_size, void* d_ws, size_t ws_size,
                              hipStream_t stream) {
    const float* x  = (const float*)d_in[0];
    const int*   nb = (const int*)d_in[1];
    const float* W1 = (const float*)d_in[2];
    const float* b1 = (const float*)d_in[3];
    const float* W2 = (const float*)d_in[4];
    const float* b2 = (const float*)d_in[5];

    char* ws = (char*)d_ws;
    unsigned short* Wf1 = (unsigned short*)(ws);                       // 64 KB
    unsigned short* Wf2 = (unsigned short*)(ws + 65536);               // 64 KB
    unsigned short* xb  = (unsigned short*)(ws + 131072);              // 12.8 MB
    unsigned short* h1  = (unsigned short*)(ws + 131072 + 12800000);   // 12.8 MB
    unsigned char*  xq  = (unsigned char*)(ws + 131072 + 25600000);    // 6.4 MB
    unsigned char*  h1q = (unsigned char*)(ws + 131072 + 32000000);    // 6.4 MB

    prep<<<32 + 6250, 256, 0, stream>>>(x, xb, xq, W1, W2, Wf1, Wf2);

    const int mgrid = (N_NODES + BM - 1) / BM;  // 1563
    sage_layer<1><<<mgrid, 256, 0, stream>>>(xb, xq, nb, Wf1, b1, h1, h1q);
    sage_layer<0><<<mgrid, 256, 0, stream>>>(h1, h1q, nb, Wf2, b2, d_out, nullptr);
}